// Round 3
// baseline (507.710 us; speedup 1.0000x reference)
//
#include <hip/hip_runtime.h>
#include <math.h>
#include <stdint.h>

#define N_SRC 8192
#define M_TGT 16384
#define DDIM  64
#define REG_P 0.05f
#define LOG2E 1.44269504088896340736f
#define LN2   0.69314718055994530942f
#define LOGM  9.70406052783923404f      // ln(16384) = 14*ln2, exact constant
#define QSPLIT 8                        // column split: 8 q-slices of 2048 cols
#define ROWS   32                       // rows per k2 block (2 MFMA row-groups)
#define NROWBLK (N_SRC / ROWS)          // 256
#define K2_GRID (NROWBLK * QSPLIT)      // 2048 blocks -> 8 blocks/CU resident

typedef __attribute__((ext_vector_type(8))) short short8;
typedef __attribute__((ext_vector_type(4))) float f32x4;

// Workspace byte offsets
#define OFF_TGT  0u                           // staged tgt bf16, frag order: 2 MB
#define OFF_SRC  (2u << 20)                   // staged src bf16, frag order: 1 MB
#define OFF_BT   (3u << 20)                   // float2[M] = {psi*c_psi, sq_t}: 128 KB
#define OFF_SQS  ((3u << 20) + (128u << 10))  // sq_s[N] fp32: 32 KB
#define OFF_PART ((3u << 20) + (160u << 10))  // k1 block partials float2[384]: 3 KB
#define OFF_L    ((3u << 20) + (168u << 10))  // l partials [N][QSPLIT] fp32: 256 KB

#define K1_BLOCKS 384                         // (1024 tgt tiles + 512 src tiles) / 4 waves

__device__ __forceinline__ unsigned short f2bf(float f) {   // RNE fp32->bf16
    unsigned u = __float_as_uint(f);
    u += 0x7fffu + ((u >> 16) & 1u);
    return (unsigned short)(u >> 16);
}

__device__ __forceinline__ float fast_exp2(float x) {
#if __has_builtin(__builtin_amdgcn_exp2f)
    return __builtin_amdgcn_exp2f(x);
#else
    return exp2f(x);
#endif
}

// k1: stage tgt+src to bf16 frag-order, per-row sq norms, packed bias feed
// (psi*c_psi, sq_t) as float2, per-block partial sums of (sq_t, psi). No atomics.
__global__ __launch_bounds__(256) void k1_stage(const float* __restrict__ src,
                                                const float* __restrict__ tgt,
                                                const float* __restrict__ psi,
                                                char* __restrict__ ws) {
    const int tid  = threadIdx.x;
    const int wave = tid >> 6;
    const int lane = tid & 63;
    const int lo   = lane & 15;           // row within 16-row tile
    const int hi   = lane >> 4;           // 8-dim group within 32-dim K-half
    const int task = blockIdx.x * 4 + wave;   // 0..1535

    const float c_psi = (1.0f / REG_P) * LOG2E;

    float sq_contrib = 0.f;   // this lane's share of sum(sq_t) (targets only)
    float ps_contrib = 0.f;   // this lane's share of sum(psi)

    if (task < 1024) {                    // tgt tile T = task
        const int T = task;
        const int j = T * 16 + lo;
        float sq = 0.f;
#pragma unroll
        for (int kk = 0; kk < 2; ++kk) {
            const float* p = tgt + (size_t)j * DDIM + kk * 32 + hi * 8;
            float4 v0 = ((const float4*)p)[0];
            float4 v1 = ((const float4*)p)[1];
            short8 pk;
            pk[0]=(short)f2bf(v0.x); pk[1]=(short)f2bf(v0.y); pk[2]=(short)f2bf(v0.z); pk[3]=(short)f2bf(v0.w);
            pk[4]=(short)f2bf(v1.x); pk[5]=(short)f2bf(v1.y); pk[6]=(short)f2bf(v1.z); pk[7]=(short)f2bf(v1.w);
            ((short8*)(ws + OFF_TGT))[(T * 2 + kk) * 64 + lane] = pk;
            sq += v0.x*v0.x + v0.y*v0.y + v0.z*v0.z + v0.w*v0.w
                + v1.x*v1.x + v1.y*v1.y + v1.z*v1.z + v1.w*v1.w;
        }
        float r = sq;
        r += __shfl_xor(r, 16); r += __shfl_xor(r, 32);   // sum over hi
        if (hi == 0) {
            float pv = psi[j];
            ((float2*)(ws + OFF_BT))[j] = make_float2(pv * c_psi, r);
            ps_contrib = pv;
        }
        sq_contrib = sq;
    } else {                              // src tile g = task - 1024
        const int g = task - 1024;
        const int i = g * 16 + lo;
        float sq = 0.f;
#pragma unroll
        for (int kk = 0; kk < 2; ++kk) {
            const float* p = src + (size_t)i * DDIM + kk * 32 + hi * 8;
            float4 v0 = ((const float4*)p)[0];
            float4 v1 = ((const float4*)p)[1];
            short8 pk;
            pk[0]=(short)f2bf(v0.x); pk[1]=(short)f2bf(v0.y); pk[2]=(short)f2bf(v0.z); pk[3]=(short)f2bf(v0.w);
            pk[4]=(short)f2bf(v1.x); pk[5]=(short)f2bf(v1.y); pk[6]=(short)f2bf(v1.z); pk[7]=(short)f2bf(v1.w);
            ((short8*)(ws + OFF_SRC))[(g * 2 + kk) * 64 + lane] = pk;
            sq += v0.x*v0.x + v0.y*v0.y + v0.z*v0.z + v0.w*v0.w
                + v1.x*v1.x + v1.y*v1.y + v1.z*v1.z + v1.w*v1.w;
        }
        float r = sq;
        r += __shfl_xor(r, 16); r += __shfl_xor(r, 32);
        if (hi == 0) ((float*)(ws + OFF_SQS))[i] = r;
    }

    // block partial: wave-reduce both values, then cross-wave via LDS
    float a = sq_contrib, b = ps_contrib;
#pragma unroll
    for (int off = 1; off < 64; off <<= 1) {
        a += __shfl_xor(a, off);
        b += __shfl_xor(b, off);
    }
    __shared__ float s_a[4], s_b[4];
    if (lane == 0) { s_a[wave] = a; s_b[wave] = b; }
    __syncthreads();
    if (tid == 0) {
        float2 out;
        out.x = s_a[0] + s_a[1] + s_a[2] + s_a[3];
        out.y = s_b[0] + s_b[1] + s_b[2] + s_b[3];
        ((float2*)(ws + OFF_PART))[blockIdx.x] = out;
    }
}

// k2: MFMA GEMM fused with sum-exp2, B fragments streamed from L2, no LDS
// staging, no barriers, NO atomics/fences in the hot path. 32 rows x 2048-col
// slice per block; each wave owns 512 cols (32 tiles) independently.
// Grid 2048 = 8 blocks/CU resident (32 waves/CU) for latency hiding;
// register budget kept <=64/wave so __launch_bounds__(256,8) holds.
__global__ __launch_bounds__(256, 8) void k2_main(char* __restrict__ ws) {
    const int tid    = threadIdx.x;
    const int lane   = tid & 63;
    const int w      = tid >> 6;
    const int rowblk = blockIdx.x >> 3;       // 0..255
    const int q      = blockIdx.x & (QSPLIT - 1);
    const int row0   = rowblk * ROWS;

    // sum of k1 block partials -> inv_cn (deterministic, in-register)
    const float2* __restrict__ part = (const float2*)(ws + OFF_PART);
    float ssq = 0.f;
#pragma unroll
    for (int k = 0; k < K1_BLOCKS / 64; ++k) ssq += part[k * 64 + lane].x;
#pragma unroll
    for (int off = 1; off < 64; off <<= 1) ssq += __shfl_xor(ssq, off);
    const float inv_cn = (float)M_TGT / ssq;
    const float c_psi  = (1.0f / REG_P) * LOG2E;     // psi scale (exp2 domain)
    const float c_sqt  = inv_cn * c_psi;             // sq_t scale
    const float alpha2 = 2.0f * c_sqt;               // cross-term scale

    // A fragments: 32 rows (2 groups), resident all kernel
    const short8* __restrict__ srcst = (const short8*)(ws + OFF_SRC);
    short8 Af[2][2];
#pragma unroll
    for (int g = 0; g < 2; ++g)
#pragma unroll
        for (int kk = 0; kk < 2; ++kk)
            Af[g][kk] = srcst[((row0 >> 4) + g) * 128 + kk * 64 + lane];

    const short8* __restrict__ tgtst = (const short8*)(ws + OFF_TGT);
    const float2* __restrict__ btp   = (const float2*)(ws + OFF_BT);

    const int T0    = q * 128 + w * 32;            // first global col-tile
    const int jlane = (T0 << 4) + (lane & 15);     // bias col for this lane

    float lsum[2][4];
#pragma unroll
    for (int g = 0; g < 2; ++g)
#pragma unroll
        for (int r = 0; r < 4; ++r) lsum[g][r] = 0.f;

    // prefetch tile 0
    short8 B0n = tgtst[(T0 * 2 + 0) * 64 + lane];
    short8 B1n = tgtst[(T0 * 2 + 1) * 64 + lane];
    float2 btn = btp[jlane];

    for (int t = 0; t < 32; ++t) {
        short8 B0 = B0n, B1 = B1n;
        float2 bt = btn;
        if (t < 31) {
            const int Tg = T0 + t + 1;
            B0n = tgtst[(Tg * 2 + 0) * 64 + lane];
            B1n = tgtst[(Tg * 2 + 1) * 64 + lane];
            btn = btp[jlane + (t + 1) * 16];
        }
        const float bias = fmaf(-c_sqt, bt.y, bt.x);   // psi*c_psi - sq_t*c_sqt
        f32x4 acc[2];
#pragma unroll
        for (int g = 0; g < 2; ++g) {
            f32x4 a = {0.f, 0.f, 0.f, 0.f};
            a = __builtin_amdgcn_mfma_f32_16x16x32_bf16(Af[g][0], B0, a, 0, 0, 0);
            a = __builtin_amdgcn_mfma_f32_16x16x32_bf16(Af[g][1], B1, a, 0, 0, 0);
            acc[g] = a;
        }
#pragma unroll
        for (int g = 0; g < 2; ++g)
#pragma unroll
            for (int r = 0; r < 4; ++r)
                lsum[g][r] += fast_exp2(fmaf(alpha2, acc[g][r], bias));
    }

    // reduce over the 16 cols per row, combine the block's 4 waves via LDS
    __shared__ float s_l[4][ROWS];
#pragma unroll
    for (int g = 0; g < 2; ++g)
#pragma unroll
        for (int r = 0; r < 4; ++r) {
            float v = lsum[g][r];
            v += __shfl_xor(v, 1); v += __shfl_xor(v, 2);
            v += __shfl_xor(v, 4); v += __shfl_xor(v, 8);
            if ((lane & 15) == 0)
                s_l[w][g * 16 + (lane >> 4) * 4 + r] = v;
        }
    __syncthreads();
    if (tid < ROWS) {
        float v = s_l[0][tid] + s_l[1][tid] + s_l[2][tid] + s_l[3][tid];
        // L transposed [N][QSPLIT] so k3 reads contiguous float4 pairs
        ((float*)(ws + OFF_L))[(size_t)(row0 + tid) * QSPLIT + q] = v;
    }
}

// k3: combine q-slices, lse, final scalar. Single 1024-thread block.
__global__ __launch_bounds__(1024) void k3_final(const char* __restrict__ ws,
                                                 float* __restrict__ out) {
    const int tid  = threadIdx.x;
    const int lane = tid & 63;

    const float2* __restrict__ part = (const float2*)(ws + OFF_PART);
    float ssq = 0.f, spsi = 0.f;
#pragma unroll
    for (int k = 0; k < K1_BLOCKS / 64; ++k) {
        float2 p = part[k * 64 + lane];
        ssq += p.x; spsi += p.y;
    }
#pragma unroll
    for (int off = 1; off < 64; off <<= 1) {
        ssq  += __shfl_xor(ssq, off);
        spsi += __shfl_xor(spsi, off);
    }
    const float inv_cn = (float)M_TGT / ssq;

    const float4* __restrict__ Lv  = (const float4*)(ws + OFF_L);
    const float*  __restrict__ sqs = (const float*)(ws + OFF_SQS);

    float acc = 0.f;
    for (int i = tid; i < N_SRC; i += 1024) {
        float4 a = Lv[i * 2 + 0];
        float4 b = Lv[i * 2 + 1];
        float lt = a.x + a.y + a.z + a.w + b.x + b.y + b.z + b.w;  // fixed order
        const float A = -sqs[i] * inv_cn * (1.0f / REG_P) - LOGM;
        acc += -REG_P * (A + LN2 * __log2f(lt));
    }
    __shared__ float red[1024];
    red[tid] = acc;
    __syncthreads();
    for (int off = 512; off > 0; off >>= 1) {
        if (tid < off) red[tid] += red[tid + off];
        __syncthreads();
    }
    if (tid == 0)
        out[0] = red[0] / (float)N_SRC + spsi / (float)M_TGT;
}

extern "C" void kernel_launch(void* const* d_in, const int* in_sizes, int n_in,
                              void* d_out, int out_size, void* d_ws, size_t ws_size,
                              hipStream_t stream) {
    const float* src = (const float*)d_in[0];   // [N, D]
    const float* tgt = (const float*)d_in[1];   // [M, D]
    const float* psi = (const float*)d_in[2];   // [M]
    char* ws = (char*)d_ws;

    k1_stage<<<K1_BLOCKS, 256, 0, stream>>>(src, tgt, psi, ws);
    k2_main<<<K2_GRID, 256, 0, stream>>>(ws);
    k3_final<<<1, 1024, 0, stream>>>(ws, (float*)d_out);
}

// Round 4
// 95.272 us; speedup vs baseline: 5.3290x; 5.3290x over previous
//
#include <hip/hip_runtime.h>
#include <math.h>
#include <stdint.h>

#define N_SRC 8192
#define M_TGT 16384
#define DDIM  64
#define REG_P 0.05f
#define LOG2E 1.44269504088896340736f
#define LN2   0.69314718055994530942f
#define LOGM  9.70406052783923404f      // ln(16384) = 14*ln2, exact constant
#define QSPLIT 8                        // column split: 128 rowblks x 8 = 1024 blocks for k2

typedef __attribute__((ext_vector_type(8))) short short8;
typedef __attribute__((ext_vector_type(4))) float f32x4;

// Workspace byte offsets
#define OFF_TGT  0u                           // staged tgt bf16, frag order: 2 MB
#define OFF_SRC  (2u << 20)                   // staged src bf16, frag order: 1 MB
#define OFF_BT   (3u << 20)                   // float2[M] = {psi*c_psi, sq_t}: 128 KB
#define OFF_SQS  ((3u << 20) + (128u << 10))  // sq_s[N] fp32: 32 KB
#define OFF_PART ((3u << 20) + (160u << 10))  // k1 block partials float2[384]: 3 KB
#define OFF_L    ((3u << 20) + (168u << 10))  // l partials [N][QSPLIT] fp32: 256 KB

#define K1_BLOCKS 384                         // (1024 tgt tiles + 512 src tiles) / 4 waves

__device__ __forceinline__ unsigned short f2bf(float f) {   // RNE fp32->bf16
    unsigned u = __float_as_uint(f);
    u += 0x7fffu + ((u >> 16) & 1u);
    return (unsigned short)(u >> 16);
}

__device__ __forceinline__ float fast_exp2(float x) {
#if __has_builtin(__builtin_amdgcn_exp2f)
    return __builtin_amdgcn_exp2f(x);
#else
    return exp2f(x);
#endif
}

// k1: stage tgt+src to bf16 frag-order, per-row sq norms, packed bias feed
// (psi*c_psi, sq_t) as float2, per-block partial sums of (sq_t, psi). No atomics.
__global__ __launch_bounds__(256) void k1_stage(const float* __restrict__ src,
                                                const float* __restrict__ tgt,
                                                const float* __restrict__ psi,
                                                char* __restrict__ ws) {
    const int tid  = threadIdx.x;
    const int wave = tid >> 6;
    const int lane = tid & 63;
    const int lo   = lane & 15;           // row within 16-row tile
    const int hi   = lane >> 4;           // 8-dim group within 32-dim K-half
    const int task = blockIdx.x * 4 + wave;   // 0..1535

    const float c_psi = (1.0f / REG_P) * LOG2E;

    float sq_contrib = 0.f;   // this lane's share of sum(sq_t) (targets only)
    float ps_contrib = 0.f;   // this lane's share of sum(psi)

    if (task < 1024) {                    // tgt tile T = task
        const int T = task;
        const int j = T * 16 + lo;
        float sq = 0.f;
#pragma unroll
        for (int kk = 0; kk < 2; ++kk) {
            const float* p = tgt + (size_t)j * DDIM + kk * 32 + hi * 8;
            float4 v0 = ((const float4*)p)[0];
            float4 v1 = ((const float4*)p)[1];
            short8 pk;
            pk[0]=(short)f2bf(v0.x); pk[1]=(short)f2bf(v0.y); pk[2]=(short)f2bf(v0.z); pk[3]=(short)f2bf(v0.w);
            pk[4]=(short)f2bf(v1.x); pk[5]=(short)f2bf(v1.y); pk[6]=(short)f2bf(v1.z); pk[7]=(short)f2bf(v1.w);
            ((short8*)(ws + OFF_TGT))[(T * 2 + kk) * 64 + lane] = pk;
            sq += v0.x*v0.x + v0.y*v0.y + v0.z*v0.z + v0.w*v0.w
                + v1.x*v1.x + v1.y*v1.y + v1.z*v1.z + v1.w*v1.w;
        }
        float r = sq;
        r += __shfl_xor(r, 16); r += __shfl_xor(r, 32);   // sum over hi
        if (hi == 0) {
            float pv = psi[j];
            ((float2*)(ws + OFF_BT))[j] = make_float2(pv * c_psi, r);
            ps_contrib = pv;
        }
        sq_contrib = sq;
    } else {                              // src tile g = task - 1024
        const int g = task - 1024;
        const int i = g * 16 + lo;
        float sq = 0.f;
#pragma unroll
        for (int kk = 0; kk < 2; ++kk) {
            const float* p = src + (size_t)i * DDIM + kk * 32 + hi * 8;
            float4 v0 = ((const float4*)p)[0];
            float4 v1 = ((const float4*)p)[1];
            short8 pk;
            pk[0]=(short)f2bf(v0.x); pk[1]=(short)f2bf(v0.y); pk[2]=(short)f2bf(v0.z); pk[3]=(short)f2bf(v0.w);
            pk[4]=(short)f2bf(v1.x); pk[5]=(short)f2bf(v1.y); pk[6]=(short)f2bf(v1.z); pk[7]=(short)f2bf(v1.w);
            ((short8*)(ws + OFF_SRC))[(g * 2 + kk) * 64 + lane] = pk;
            sq += v0.x*v0.x + v0.y*v0.y + v0.z*v0.z + v0.w*v0.w
                + v1.x*v1.x + v1.y*v1.y + v1.z*v1.z + v1.w*v1.w;
        }
        float r = sq;
        r += __shfl_xor(r, 16); r += __shfl_xor(r, 32);
        if (hi == 0) ((float*)(ws + OFF_SQS))[i] = r;
    }

    // block partial: wave-reduce both values, then cross-wave via LDS
    float a = sq_contrib, b = ps_contrib;
#pragma unroll
    for (int off = 1; off < 64; off <<= 1) {
        a += __shfl_xor(a, off);
        b += __shfl_xor(b, off);
    }
    __shared__ float s_a[4], s_b[4];
    if (lane == 0) { s_a[wave] = a; s_b[wave] = b; }
    __syncthreads();
    if (tid == 0) {
        float2 out;
        out.x = s_a[0] + s_a[1] + s_a[2] + s_a[3];
        out.y = s_b[0] + s_b[1] + s_b[2] + s_b[3];
        ((float2*)(ws + OFF_PART))[blockIdx.x] = out;
    }
}

// k2: MFMA GEMM fused with sum-exp2, B fragments streamed from L2, no LDS
// staging, no barriers in the hot loop, no atomics. 64 rows x 2048-col slice
// per block; each wave owns 512 cols (32 tiles) independently.
// __launch_bounds__(256,4): 128-VGPR budget, compiler uses ~56, zero spills
// (round-0-verified geometry; (256,8) caused catastrophic scratch spilling).
__global__ __launch_bounds__(256, 4) void k2_main(char* __restrict__ ws) {
    const int tid    = threadIdx.x;
    const int lane   = tid & 63;
    const int w      = tid >> 6;
    const int rowblk = blockIdx.x >> 3;
    const int q      = blockIdx.x & (QSPLIT - 1);
    const int row0   = rowblk * 64;

    // sum of k1 block partials -> inv_cn (deterministic, in-register)
    const float2* __restrict__ part = (const float2*)(ws + OFF_PART);
    float ssq = 0.f;
#pragma unroll
    for (int k = 0; k < K1_BLOCKS / 64; ++k) ssq += part[k * 64 + lane].x;
#pragma unroll
    for (int off = 1; off < 64; off <<= 1) ssq += __shfl_xor(ssq, off);
    const float inv_cn = (float)M_TGT / ssq;
    const float c_psi  = (1.0f / REG_P) * LOG2E;     // psi scale (exp2 domain)
    const float c_sqt  = inv_cn * c_psi;             // sq_t scale
    const float alpha2 = 2.0f * c_sqt;               // cross-term scale

    // A fragments: 64 rows, resident all kernel
    const short8* __restrict__ srcst = (const short8*)(ws + OFF_SRC);
    short8 Af[4][2];
#pragma unroll
    for (int g = 0; g < 4; ++g)
#pragma unroll
        for (int kk = 0; kk < 2; ++kk)
            Af[g][kk] = srcst[((row0 >> 4) + g) * 128 + kk * 64 + lane];

    const short8* __restrict__ tgtst = (const short8*)(ws + OFF_TGT);
    const float2* __restrict__ btp   = (const float2*)(ws + OFF_BT);

    const int T0    = (q * 2048 + w * 512) >> 4;   // first global col-tile
    const int jlane = (T0 << 4) + (lane & 15);     // bias col for this lane

    float lsum[4][4];
#pragma unroll
    for (int g = 0; g < 4; ++g)
#pragma unroll
        for (int r = 0; r < 4; ++r) lsum[g][r] = 0.f;

    // prefetch tile 0
    short8 B0n = tgtst[(T0 * 2 + 0) * 64 + lane];
    short8 B1n = tgtst[(T0 * 2 + 1) * 64 + lane];
    float2 btn = btp[jlane];

    for (int t = 0; t < 32; ++t) {
        short8 B0 = B0n, B1 = B1n;
        float2 bt = btn;
        if (t < 31) {
            const int Tg = T0 + t + 1;
            B0n = tgtst[(Tg * 2 + 0) * 64 + lane];
            B1n = tgtst[(Tg * 2 + 1) * 64 + lane];
            btn = btp[jlane + (t + 1) * 16];
        }
        const float bias = fmaf(-c_sqt, bt.y, bt.x);   // psi*c_psi - sq_t*c_sqt
        f32x4 acc[4];
#pragma unroll
        for (int g = 0; g < 4; ++g) {
            f32x4 a = {0.f, 0.f, 0.f, 0.f};
            a = __builtin_amdgcn_mfma_f32_16x16x32_bf16(Af[g][0], B0, a, 0, 0, 0);
            a = __builtin_amdgcn_mfma_f32_16x16x32_bf16(Af[g][1], B1, a, 0, 0, 0);
            acc[g] = a;
        }
#pragma unroll
        for (int g = 0; g < 4; ++g)
#pragma unroll
            for (int r = 0; r < 4; ++r)
                lsum[g][r] += fast_exp2(fmaf(alpha2, acc[g][r], bias));
    }

    // reduce over the 16 cols per row, combine the block's 4 waves via LDS
    __shared__ float s_l[4][64];
#pragma unroll
    for (int g = 0; g < 4; ++g)
#pragma unroll
        for (int r = 0; r < 4; ++r) {
            float v = lsum[g][r];
            v += __shfl_xor(v, 1); v += __shfl_xor(v, 2);
            v += __shfl_xor(v, 4); v += __shfl_xor(v, 8);
            if ((lane & 15) == 0)
                s_l[w][g * 16 + (lane >> 4) * 4 + r] = v;
        }
    __syncthreads();
    if (tid < 64) {
        float v = s_l[0][tid] + s_l[1][tid] + s_l[2][tid] + s_l[3][tid];
        // L transposed [N][QSPLIT] so k3 reads contiguous float4 pairs
        ((float*)(ws + OFF_L))[(size_t)(row0 + tid) * QSPLIT + q] = v;
    }
}

// k3: combine q-slices, lse, final scalar. Single 1024-thread block.
__global__ __launch_bounds__(1024) void k3_final(const char* __restrict__ ws,
                                                 float* __restrict__ out) {
    const int tid  = threadIdx.x;
    const int lane = tid & 63;

    const float2* __restrict__ part = (const float2*)(ws + OFF_PART);
    float ssq = 0.f, spsi = 0.f;
#pragma unroll
    for (int k = 0; k < K1_BLOCKS / 64; ++k) {
        float2 p = part[k * 64 + lane];
        ssq += p.x; spsi += p.y;
    }
#pragma unroll
    for (int off = 1; off < 64; off <<= 1) {
        ssq  += __shfl_xor(ssq, off);
        spsi += __shfl_xor(spsi, off);
    }
    const float inv_cn = (float)M_TGT / ssq;

    const float4* __restrict__ Lv  = (const float4*)(ws + OFF_L);
    const float*  __restrict__ sqs = (const float*)(ws + OFF_SQS);

    float acc = 0.f;
    for (int i = tid; i < N_SRC; i += 1024) {
        float4 a = Lv[i * 2 + 0];
        float4 b = Lv[i * 2 + 1];
        float lt = a.x + a.y + a.z + a.w + b.x + b.y + b.z + b.w;  // fixed order
        const float A = -sqs[i] * inv_cn * (1.0f / REG_P) - LOGM;
        acc += -REG_P * (A + LN2 * __log2f(lt));
    }
    __shared__ float red[1024];
    red[tid] = acc;
    __syncthreads();
    for (int off = 512; off > 0; off >>= 1) {
        if (tid < off) red[tid] += red[tid + off];
        __syncthreads();
    }
    if (tid == 0)
        out[0] = red[0] / (float)N_SRC + spsi / (float)M_TGT;
}

extern "C" void kernel_launch(void* const* d_in, const int* in_sizes, int n_in,
                              void* d_out, int out_size, void* d_ws, size_t ws_size,
                              hipStream_t stream) {
    const float* src = (const float*)d_in[0];   // [N, D]
    const float* tgt = (const float*)d_in[1];   // [M, D]
    const float* psi = (const float*)d_in[2];   // [M]
    char* ws = (char*)d_ws;

    k1_stage<<<K1_BLOCKS, 256, 0, stream>>>(src, tgt, psi, ws);
    k2_main<<<(N_SRC / 64) * QSPLIT, 256, 0, stream>>>(ws);
    k3_final<<<1, 1024, 0, stream>>>(ws, (float*)d_out);
}